// Round 1
// baseline (98.625 us; speedup 1.0000x reference)
//
#include <hip/hip_runtime.h>

#define Bn 32
#define Tn 16384
#define Ln 16
#define Sn 128
#define Hn 512
#define Cn 10
#define Kn 48
#define TOUT 16369
#define CH 1024
#define NCH 16
#define XBP 8224   // dwords per (b,ch) row of xbf (8192 + 32 zero pad)

typedef short  s16x8  __attribute__((ext_vector_type(8)));
typedef float  f32x16 __attribute__((ext_vector_type(16)));

static __device__ __forceinline__ unsigned short f2bf(float f) {
    union { float f; unsigned int u; } v; v.f = f;
    unsigned int r = v.u + 0x7FFF + ((v.u >> 16) & 1);   // RNE
    return (unsigned short)(r >> 16);
}
static __device__ __forceinline__ float bf2f(unsigned short b) {
    union { unsigned int u; float f; } v; v.u = ((unsigned int)b) << 16;
    return v.f;
}
static __device__ __forceinline__ unsigned int pk(float a, float b) {
    return (unsigned int)f2bf(a) | ((unsigned int)f2bf(b) << 16);
}
static __device__ __forceinline__ unsigned int pk2(unsigned short a, unsigned short b) {
    return (unsigned int)a | ((unsigned int)b << 16);
}
static __device__ __forceinline__ s16x8 mk_a(unsigned int d0, unsigned int d1,
                                             unsigned int d2, unsigned int d3) {
    union { unsigned int u[4]; s16x8 v; } t;
    t.u[0] = d0; t.u[1] = d1; t.u[2] = d2; t.u[3] = d3;
    return t.v;
}

// ------------------------------------------------------------------ prologue
// Cheap memory-bound precompute at full occupancy. R12 proved fusing this
// into dist costs ~+8us (conversion VALU at 8 waves/CU) vs ~-2.5us saved.
// R13: wsqT transpose now staged through LDS -> 256B-contiguous float4 row
// stores instead of 4B stores at 4KB stride (64 lines per store instr).
__global__ __launch_bounds__(256) void prep_kernel(const float* __restrict__ x,
                                                   const float* __restrict__ sh,
                                                   const float* __restrict__ b2,
                                                   unsigned int* __restrict__ shb,
                                                   float* __restrict__ shsq_g,
                                                   float* __restrict__ wsqT,
                                                   unsigned int* __restrict__ xbf,
                                                   float* __restrict__ out) {
    __shared__ float wtile[16][65];          // [r][col-in-slab], pad 65 vs banks
    const int tid = threadIdx.x;
    if (blockIdx.x == 0) {
        if (tid < 128) {
            const float4* r4 = (const float4*)(sh + tid * Kn);
            float v[48]; float q = 0.f;
            #pragma unroll
            for (int c = 0; c < 12; ++c) {
                const float4 t = r4[c];
                v[4*c] = t.x; v[4*c+1] = t.y; v[4*c+2] = t.z; v[4*c+3] = t.w;
                q = fmaf(t.x, t.x, q); q = fmaf(t.y, t.y, q);
                q = fmaf(t.z, t.z, q); q = fmaf(t.w, t.w, q);
            }
            shsq_g[tid] = q;
            uint4* dst = (uint4*)(shb + tid * 24);
            #pragma unroll
            for (int c = 0; c < 6; ++c) {
                uint4 o;
                o.x = pk(-2.f*v[8*c  ], -2.f*v[8*c+1]);
                o.y = pk(-2.f*v[8*c+2], -2.f*v[8*c+3]);
                o.z = pk(-2.f*v[8*c+4], -2.f*v[8*c+5]);
                o.w = pk(-2.f*v[8*c+6], -2.f*v[8*c+7]);
                dst[c] = o;
            }
        } else if (tid < 224) {
            const int r = tid - 128;             // 96 rows: zero 32-dword pads
            uint4* d = (uint4*)(xbf + r * XBP + 8192);
            const uint4 z = {0u, 0u, 0u, 0u};
            #pragma unroll
            for (int q = 0; q < 8; ++q) d[q] = z;
        } else {
            const int k0 = (tid - 224) * 10;     // init out[cls] = b2 (mlp atomicAdds)
            #pragma unroll
            for (int c = 0; c < Cn; ++c) out[Bn * Sn + k0 + c] = b2[c];
        }
        return;
    }
    // blocks 1..512: (b, 1024-t slab); thread owns 4 t
    const int bid  = blockIdx.x - 1;
    const int b    = bid >> 4;
    const int slab = bid & 15;
    const int t0   = (slab << 10) + 4 * tid;
    float q[4] = {0.f, 0.f, 0.f, 0.f};
    #pragma unroll
    for (int ch = 0; ch < 3; ++ch) {
        const float* xs = x + (b * 3 + ch) * Tn + t0;
        float wv[20];
        if (t0 + 20 <= Tn) {
            const float4* x4 = (const float4*)xs;
            #pragma unroll
            for (int c = 0; c < 5; ++c) {
                const float4 t = x4[c];
                wv[4*c] = t.x; wv[4*c+1] = t.y; wv[4*c+2] = t.z; wv[4*c+3] = t.w;
            }
        } else {
            #pragma unroll
            for (int k = 0; k < 20; ++k) wv[k] = (t0 + k < Tn) ? xs[k] : 0.f;
        }
        float s = 0.f;
        #pragma unroll
        for (int l = 0; l < 16; ++l) s = fmaf(wv[l], wv[l], s);
        q[0] += s;
        #pragma unroll
        for (int j = 1; j < 4; ++j) {
            s = s - wv[j-1]*wv[j-1] + wv[j+15]*wv[j+15];
            q[j] += s;
        }
        uint2 o = { pk(wv[0], wv[1]), pk(wv[2], wv[3]) };
        *(uint2*)(xbf + (b * 3 + ch) * XBP + (t0 >> 1)) = o;
    }
    // transpose-stage: thread owns rows r0..r0+3 of col cc; block = full slab
    const int r0 = t0 & 15, cc = tid >> 2;
    #pragma unroll
    for (int c = 0; c < 4; ++c)
        wtile[r0 + c][cc] = (t0 + c >= TOUT) ? 1e30f : q[c];
    __syncthreads();
    // coalesced write-out: 16 threads per row, 256B contiguous per row
    const int row = tid >> 4, c4 = (tid & 15) * 4;
    float4 v;
    v.x = wtile[row][c4];     v.y = wtile[row][c4 + 1];
    v.z = wtile[row][c4 + 2]; v.w = wtile[row][c4 + 3];
    *(float4*)(wsqT + b * 16384 + row * 1024 + slab * 64 + c4) = v;
}

// ---------------------------------------------------------------- distance
// R10/R12 proved a 4-wave block at (256,3) only gets ~84 arch-VGPRs (unified
// file) and spills ~100MB scratch (R10: 64us); (256,2) budget ~168 fit the
// ~110-reg live set at 2 waves/SIMD. R13: same live set, but 1-wave blocks
// with __launch_bounds__(64,3) -> budget 512/3=170 (no spill) at 3 waves/SIMD
// (+50% latency hiding), zero LDS, no __syncthreads, no rigid 2-batch
// schedule (4096 blocks drain smoothly). Each wave writes its own partial
// slice; mlp absorbs the extra 4x reduction (+0.25us traffic).
__global__ __launch_bounds__(64, 3) void dist_kernel(const unsigned int* __restrict__ shb,
                                                     const float* __restrict__ shsq_g,
                                                     const float* __restrict__ wsqT,
                                                     const unsigned int* __restrict__ xbf,
                                                     float* __restrict__ partial) {
    const int lane  = threadIdx.x;
    const int w     = blockIdx.x & 3;            // t-subblock (was wave id)
    const int half  = (blockIdx.x >> 2) & 1;     // S-half: columns half*64 .. +63
    const int chunk = (blockIdx.x >> 3) & 15;
    const int b     = blockIdx.x >> 7;
    const int tb    = chunk * CH;
    const int n     = lane & 31;
    const int h     = lane >> 5;

    // ---- B-fragments: 3 data channels + winsq/shsq channel b4
    s16x8 bfr[3][2], b4[2];
    #pragma unroll
    for (int st = 0; st < 2; ++st) {
        const int s = half * 64 + st * 32 + n;
        const uint4* base = (const uint4*)(shb + s * 24);
        #pragma unroll
        for (int kk = 0; kk < 3; ++kk) {
            const uint4 t = base[kk * 2 + h];
            bfr[kk][st] = mk_a(t.x, t.y, t.z, t.w);
        }
        const float q = shsq_g[s];
        const unsigned short qh = f2bf(q);
        const unsigned short ql = f2bf(q - bf2f(qh));
        b4[st] = h ? mk_a(0u, 0u, 0u, 0u)
                   : mk_a(0x3F803F80u, pk2(qh, ql), 0u, 0u);
    }

    // ---- rr-invariant 16-elem bf16 window per channel (16-B aligned loads)
    unsigned int u[3][8];
    {
        const int D0 = (tb >> 1) + 4 * (w & 1) + ((w >> 1) << 8) + 8 * n + 4 * h;
        #pragma unroll
        for (int ch = 0; ch < 3; ++ch) {
            const unsigned int* xr = xbf + (b * 3 + ch) * XBP + D0;
            const uint4 lo = *(const uint4*)(xr);
            const uint4 hi = *(const uint4*)(xr + 4);
            u[ch][0] = lo.x; u[ch][1] = lo.y; u[ch][2] = lo.z; u[ch][3] = lo.w;
            u[ch][4] = hi.x; u[ch][5] = hi.y; u[ch][6] = hi.z; u[ch][7] = hi.w;
        }
    }

    // ---- main loop: 8 tiles, 8 MFMA each (4 per st incl. the w/shsq channel)
    float mcol[2] = {1e30f, 1e30f};
    const f32x16 zero16 = {0.f, 0.f, 0.f, 0.f, 0.f, 0.f, 0.f, 0.f,
                           0.f, 0.f, 0.f, 0.f, 0.f, 0.f, 0.f, 0.f};
    const int   base_t = 8 * (w & 1) + ((w >> 1) << 9);
    const float* wbase = wsqT + b * 16384 + (tb >> 4) + n;

    #pragma unroll
    for (int rr = 0; rr < 8; ++rr) {
        const int i = base_t + rr;
        s16x8 a[3];
        #pragma unroll
        for (int ch = 0; ch < 3; ++ch) {
            if ((rr & 1) == 0) {
                a[ch] = mk_a(u[ch][rr/2], u[ch][rr/2+1], u[ch][rr/2+2], u[ch][rr/2+3]);
            } else {
                unsigned int d[4];
                #pragma unroll
                for (int k = 0; k < 4; ++k)
                    d[k] = (u[ch][rr/2 + k] >> 16) | (u[ch][rr/2 + k + 1] << 16);
                a[ch] = mk_a(d[0], d[1], d[2], d[3]);
            }
        }
        // winsq channel: coalesced per-lane load + hi/lo bf16 split
        const float wv = wbase[(i & 15) * 1024 + ((i >> 9) << 5)];
        const unsigned short wh = f2bf(wv);
        const unsigned short wl = f2bf(wv - bf2f(wh));
        const s16x8 a4 = h ? mk_a(0u, 0u, 0u, 0u)
                           : mk_a(pk2(wh, wl), 0x3F803F80u, 0u, 0u);

        #pragma unroll
        for (int st = 0; st < 2; ++st) {
            f32x16 acc;
            acc = __builtin_amdgcn_mfma_f32_32x32x16_bf16(a[0], bfr[0][st], zero16, 0, 0, 0);
            acc = __builtin_amdgcn_mfma_f32_32x32x16_bf16(a[1], bfr[1][st], acc, 0, 0, 0);
            acc = __builtin_amdgcn_mfma_f32_32x32x16_bf16(a[2], bfr[2][st], acc, 0, 0, 0);
            acc = __builtin_amdgcn_mfma_f32_32x32x16_bf16(a4,   b4[st],    acc, 0, 0, 0);
            #pragma unroll
            for (int reg = 0; reg < 16; reg += 2)
                mcol[st] = fminf(fminf(mcol[st], acc[reg]), acc[reg + 1]);   // v_min3
        }
    }

    // ---- reduce: lanes n / n+32 share column; one partial row per wave
    #pragma unroll
    for (int st = 0; st < 2; ++st) {
        float mm = fminf(mcol[st], __shfl_xor(mcol[st], 32, 64));
        if (h == 0)
            partial[((b * NCH + chunk) * 4 + w) * Sn + half * 64 + st * 32 + n] = mm;
    }
}

// ------------------------- final min + MLP, H split over 4 blocks per batch
__global__ __launch_bounds__(512) void mlp_kernel(const float* __restrict__ partial,
                                                  const float* __restrict__ W1,
                                                  const float* __restrict__ b1,
                                                  const float* __restrict__ W2,
                                                  float* __restrict__ out) {
    __shared__ float pmin[4][Sn];
    __shared__ float db[Sn];
    __shared__ float hb[128];
    __shared__ float part[Cn][32];
    const int b = blockIdx.x >> 2, g = blockIdx.x & 3, tid = threadIdx.x;

    {   // 64 partial rows per b (16 chunks x 4 t-subblocks)
        const int s = tid & 127, cg = tid >> 7;
        const float* pp = partial + (b * NCH * 4 + cg * 16) * Sn + s;
        float m = pp[0];
        #pragma unroll
        for (int c = 1; c < 16; ++c) m = fminf(m, pp[c * Sn]);
        pmin[cg][s] = m;
    }
    __syncthreads();
    if (tid < Sn) {
        const float m = fminf(fminf(pmin[0][tid], pmin[1][tid]),
                              fminf(pmin[2][tid], pmin[3][tid]));
        db[tid] = m;
        if (g == 0) out[b * Sn + tid] = m;     // distance output
    }
    __syncthreads();

    if (tid < 128) {                            // h rows g*128 .. +127
        const int hrow = g * 128 + tid;
        float a = b1[hrow];
        const float4* w1r = (const float4*)(W1 + hrow * Sn);
        const float4* dbv = (const float4*)db;
        #pragma unroll
        for (int i = 0; i < Sn / 4; ++i) {
            const float4 wv = w1r[i];
            const float4 dv = dbv[i];
            a = fmaf(dv.x, wv.x, a); a = fmaf(dv.y, wv.y, a);
            a = fmaf(dv.z, wv.z, a); a = fmaf(dv.w, wv.w, a);
        }
        hb[tid] = fmaxf(a, 0.0f);
    }
    __syncthreads();

    if (tid < Cn * 32) {
        const int c = tid >> 5, p = tid & 31;
        float acc = 0.f;
        #pragma unroll
        for (int k = 0; k < 4; ++k)
            acc = fmaf(hb[p + 32 * k], W2[c * Hn + g * 128 + p + 32 * k], acc);
        part[c][p] = acc;
    }
    __syncthreads();
    if (tid < Cn) {
        float acc = 0.f;
        #pragma unroll
        for (int p = 0; p < 32; ++p) acc += part[tid][p];
        atomicAdd(&out[Bn * Sn + b * Cn + tid], acc);   // b2 pre-added by prep
    }
}

// ----------------------------------------------------------------- launcher
extern "C" void kernel_launch(void* const* d_in, const int* in_sizes, int n_in,
                              void* d_out, int out_size, void* d_ws, size_t ws_size,
                              hipStream_t stream) {
    const float* x  = (const float*)d_in[0];
    const float* sh = (const float*)d_in[1];
    const float* W1 = (const float*)d_in[2];
    const float* b1 = (const float*)d_in[3];
    const float* W2 = (const float*)d_in[4];
    const float* b2 = (const float*)d_in[5];
    float* out = (float*)d_out;

    char* wsb = (char*)d_ws;
    float*        partial = (float*)wsb;                     // 1048576 B (2048 rows x 128)
    unsigned int* shb     = (unsigned int*)(wsb + 1048576);  //   12288 B
    float*        shsq_g  = (float*)(wsb + 1060864);         //     512 B
    float*        wsqT    = (float*)(wsb + 1061376);         //    2 MiB
    unsigned int* xbf     = (unsigned int*)(wsb + 3158528);  //  3.2 MiB

    prep_kernel<<<513, 256, 0, stream>>>(x, sh, b2, shb, shsq_g, wsqT, xbf, out);
    dist_kernel<<<Bn * NCH * 2 * 4, 64, 0, stream>>>(shb, shsq_g, wsqT, xbf, partial);
    mlp_kernel<<<Bn * 4, 512, 0, stream>>>(partial, W1, b1, W2, out);
}

// Round 3
// 84.617 us; speedup vs baseline: 1.1655x; 1.1655x over previous
//
#include <hip/hip_runtime.h>

#define Bn 32
#define Tn 16384
#define Ln 16
#define Sn 128
#define Hn 512
#define Cn 10
#define Kn 48
#define TOUT 16369
#define CH 1024
#define NCH 16
#define XBP 8224   // dwords per (b,ch) row of xbf (8192 + 32 zero pad)

typedef short  s16x8  __attribute__((ext_vector_type(8)));
typedef float  f32x16 __attribute__((ext_vector_type(16)));

static __device__ __forceinline__ unsigned short f2bf(float f) {
    union { float f; unsigned int u; } v; v.f = f;
    unsigned int r = v.u + 0x7FFF + ((v.u >> 16) & 1);   // RNE
    return (unsigned short)(r >> 16);
}
static __device__ __forceinline__ float bf2f(unsigned short b) {
    union { unsigned int u; float f; } v; v.u = ((unsigned int)b) << 16;
    return v.f;
}
static __device__ __forceinline__ unsigned int pk(float a, float b) {
    return (unsigned int)f2bf(a) | ((unsigned int)f2bf(b) << 16);
}
static __device__ __forceinline__ unsigned int pk2(unsigned short a, unsigned short b) {
    return (unsigned int)a | ((unsigned int)b << 16);
}
static __device__ __forceinline__ s16x8 mk_a(unsigned int d0, unsigned int d1,
                                             unsigned int d2, unsigned int d3) {
    union { unsigned int u[4]; s16x8 v; } t;
    t.u[0] = d0; t.u[1] = d1; t.u[2] = d2; t.u[3] = d3;
    return t.v;
}

// ------------------------------------------------------------------ prologue
// Cheap memory-bound precompute at full occupancy. R12 proved fusing this
// into dist costs ~+8us (conversion VALU at 8 waves/CU) vs ~-2.5us saved.
// R14: REVERTED to R0-exact source. R13's two edits (1-wave dist blocks,
// prep LDS transpose) cost ~+7us beyond machine noise. Timed window is
// 2x 256MiB poison fills (~82us @ 75-82% HBM write peak) + ~3.4us kernels.
// R15: unchanged resubmit — R14's bench was an infra failure (container).
__global__ __launch_bounds__(256) void prep_kernel(const float* __restrict__ x,
                                                   const float* __restrict__ sh,
                                                   const float* __restrict__ b2,
                                                   unsigned int* __restrict__ shb,
                                                   float* __restrict__ shsq_g,
                                                   float* __restrict__ wsqT,
                                                   unsigned int* __restrict__ xbf,
                                                   float* __restrict__ out) {
    const int tid = threadIdx.x;
    if (blockIdx.x == 0) {
        if (tid < 128) {
            const float4* r4 = (const float4*)(sh + tid * Kn);
            float v[48]; float q = 0.f;
            #pragma unroll
            for (int c = 0; c < 12; ++c) {
                const float4 t = r4[c];
                v[4*c] = t.x; v[4*c+1] = t.y; v[4*c+2] = t.z; v[4*c+3] = t.w;
                q = fmaf(t.x, t.x, q); q = fmaf(t.y, t.y, q);
                q = fmaf(t.z, t.z, q); q = fmaf(t.w, t.w, q);
            }
            shsq_g[tid] = q;
            uint4* dst = (uint4*)(shb + tid * 24);
            #pragma unroll
            for (int c = 0; c < 6; ++c) {
                uint4 o;
                o.x = pk(-2.f*v[8*c  ], -2.f*v[8*c+1]);
                o.y = pk(-2.f*v[8*c+2], -2.f*v[8*c+3]);
                o.z = pk(-2.f*v[8*c+4], -2.f*v[8*c+5]);
                o.w = pk(-2.f*v[8*c+6], -2.f*v[8*c+7]);
                dst[c] = o;
            }
        } else if (tid < 224) {
            const int r = tid - 128;             // 96 rows: zero 32-dword pads
            uint4* d = (uint4*)(xbf + r * XBP + 8192);
            const uint4 z = {0u, 0u, 0u, 0u};
            #pragma unroll
            for (int q = 0; q < 8; ++q) d[q] = z;
        } else {
            const int k0 = (tid - 224) * 10;     // init out[cls] = b2 (mlp atomicAdds)
            #pragma unroll
            for (int c = 0; c < Cn; ++c) out[Bn * Sn + k0 + c] = b2[c];
        }
        return;
    }
    // blocks 1..512: (b, 1024-t slab); thread owns 4 t
    const int bid = blockIdx.x - 1;
    const int b   = bid >> 4;
    const int t0  = ((bid & 15) << 10) + 4 * tid;
    float q[4] = {0.f, 0.f, 0.f, 0.f};
    #pragma unroll
    for (int ch = 0; ch < 3; ++ch) {
        const float* xs = x + (b * 3 + ch) * Tn + t0;
        float wv[20];
        if (t0 + 20 <= Tn) {
            const float4* x4 = (const float4*)xs;
            #pragma unroll
            for (int c = 0; c < 5; ++c) {
                const float4 t = x4[c];
                wv[4*c] = t.x; wv[4*c+1] = t.y; wv[4*c+2] = t.z; wv[4*c+3] = t.w;
            }
        } else {
            #pragma unroll
            for (int k = 0; k < 20; ++k) wv[k] = (t0 + k < Tn) ? xs[k] : 0.f;
        }
        float s = 0.f;
        #pragma unroll
        for (int l = 0; l < 16; ++l) s = fmaf(wv[l], wv[l], s);
        q[0] += s;
        #pragma unroll
        for (int j = 1; j < 4; ++j) {
            s = s - wv[j-1]*wv[j-1] + wv[j+15]*wv[j+15];
            q[j] += s;
        }
        uint2 o = { pk(wv[0], wv[1]), pk(wv[2], wv[3]) };
        *(uint2*)(xbf + (b * 3 + ch) * XBP + (t0 >> 1)) = o;
    }
    const int r0 = t0 & 15, col = t0 >> 4;
    float* wrow = wsqT + b * 16384 + col;
    #pragma unroll
    for (int c = 0; c < 4; ++c)
        wrow[(r0 + c) * 1024] = (t0 + c >= TOUT) ? 1e30f : q[c];
}

// ---------------------------------------------------------------- distance
// (256,2): R10/R12 proved the (256,3) arch-VGPR budget is only ~84 (unified
// file reserves the rest for accum) — this kernel's ~110-reg live set spills
// ~100MB scratch there (R10: 64us). (256,2) budget ~168 fits. DO NOT raise.
// R13 ALSO proved: 1-wave blocks at __launch_bounds__(64,3) regress ~+7us
// (workgroup-slot pressure / lost intra-block L1 locality). DO NOT split.
__global__ __launch_bounds__(256, 2) void dist_kernel(const unsigned int* __restrict__ shb,
                                                      const float* __restrict__ shsq_g,
                                                      const float* __restrict__ wsqT,
                                                      const unsigned int* __restrict__ xbf,
                                                      float* __restrict__ partial) {
    __shared__ float wavemin[4 * 64];

    const int tid   = threadIdx.x;
    const int b     = blockIdx.x >> 5;
    const int rem   = blockIdx.x & 31;
    const int chunk = rem >> 1;
    const int half  = rem & 1;                   // S-half: columns half*64 .. +63
    const int tb    = chunk * CH;
    const int lane  = tid & 63;
    const int w     = tid >> 6;
    const int n     = lane & 31;
    const int h     = lane >> 5;

    // ---- B-fragments: 3 data channels + winsq/shsq channel b4
    s16x8 bfr[3][2], b4[2];
    #pragma unroll
    for (int st = 0; st < 2; ++st) {
        const int s = half * 64 + st * 32 + n;
        const uint4* base = (const uint4*)(shb + s * 24);
        #pragma unroll
        for (int kk = 0; kk < 3; ++kk) {
            const uint4 t = base[kk * 2 + h];
            bfr[kk][st] = mk_a(t.x, t.y, t.z, t.w);
        }
        const float q = shsq_g[s];
        const unsigned short qh = f2bf(q);
        const unsigned short ql = f2bf(q - bf2f(qh));
        b4[st] = h ? mk_a(0u, 0u, 0u, 0u)
                   : mk_a(0x3F803F80u, pk2(qh, ql), 0u, 0u);
    }

    // ---- rr-invariant 16-elem bf16 window per channel (16-B aligned loads)
    unsigned int u[3][8];
    {
        const int D0 = (tb >> 1) + 4 * (w & 1) + ((w >> 1) << 8) + 8 * n + 4 * h;
        #pragma unroll
        for (int ch = 0; ch < 3; ++ch) {
            const unsigned int* xr = xbf + (b * 3 + ch) * XBP + D0;
            const uint4 lo = *(const uint4*)(xr);
            const uint4 hi = *(const uint4*)(xr + 4);
            u[ch][0] = lo.x; u[ch][1] = lo.y; u[ch][2] = lo.z; u[ch][3] = lo.w;
            u[ch][4] = hi.x; u[ch][5] = hi.y; u[ch][6] = hi.z; u[ch][7] = hi.w;
        }
    }

    // ---- main loop: 8 tiles, 8 MFMA each (4 per st incl. the w/shsq channel)
    float mcol[2] = {1e30f, 1e30f};
    const f32x16 zero16 = {0.f, 0.f, 0.f, 0.f, 0.f, 0.f, 0.f, 0.f,
                           0.f, 0.f, 0.f, 0.f, 0.f, 0.f, 0.f, 0.f};
    const int   base_t = 8 * (w & 1) + ((w >> 1) << 9);
    const float* wbase = wsqT + b * 16384 + (tb >> 4) + n;

    #pragma unroll
    for (int rr = 0; rr < 8; ++rr) {
        const int i = base_t + rr;
        s16x8 a[3];
        #pragma unroll
        for (int ch = 0; ch < 3; ++ch) {
            if ((rr & 1) == 0) {
                a[ch] = mk_a(u[ch][rr/2], u[ch][rr/2+1], u[ch][rr/2+2], u[ch][rr/2+3]);
            } else {
                unsigned int d[4];
                #pragma unroll
                for (int k = 0; k < 4; ++k)
                    d[k] = (u[ch][rr/2 + k] >> 16) | (u[ch][rr/2 + k + 1] << 16);
                a[ch] = mk_a(d[0], d[1], d[2], d[3]);
            }
        }
        // winsq channel: coalesced per-lane load + hi/lo bf16 split
        const float wv = wbase[(i & 15) * 1024 + ((i >> 9) << 5)];
        const unsigned short wh = f2bf(wv);
        const unsigned short wl = f2bf(wv - bf2f(wh));
        const s16x8 a4 = h ? mk_a(0u, 0u, 0u, 0u)
                           : mk_a(pk2(wh, wl), 0x3F803F80u, 0u, 0u);

        #pragma unroll
        for (int st = 0; st < 2; ++st) {
            f32x16 acc;
            acc = __builtin_amdgcn_mfma_f32_32x32x16_bf16(a[0], bfr[0][st], zero16, 0, 0, 0);
            acc = __builtin_amdgcn_mfma_f32_32x32x16_bf16(a[1], bfr[1][st], acc, 0, 0, 0);
            acc = __builtin_amdgcn_mfma_f32_32x32x16_bf16(a[2], bfr[2][st], acc, 0, 0, 0);
            acc = __builtin_amdgcn_mfma_f32_32x32x16_bf16(a4,   b4[st],    acc, 0, 0, 0);
            #pragma unroll
            for (int reg = 0; reg < 16; reg += 2)
                mcol[st] = fminf(fminf(mcol[st], acc[reg]), acc[reg + 1]);   // v_min3
        }
    }

    // ---- reduce: lanes n / n+32 share column
    #pragma unroll
    for (int st = 0; st < 2; ++st) {
        float mm = mcol[st];
        mm = fminf(mm, __shfl_xor(mm, 32, 64));
        if (h == 0) wavemin[w * 64 + st * 32 + n] = mm;
    }
    __syncthreads();
    if (tid < 64) {
        const float mm = fminf(fminf(wavemin[tid], wavemin[64 + tid]),
                               fminf(wavemin[128 + tid], wavemin[192 + tid]));
        partial[(b * NCH + chunk) * Sn + half * 64 + tid] = mm;
    }
}

// ------------------------- final min + MLP, H split over 4 blocks per batch
__global__ __launch_bounds__(512) void mlp_kernel(const float* __restrict__ partial,
                                                  const float* __restrict__ W1,
                                                  const float* __restrict__ b1,
                                                  const float* __restrict__ W2,
                                                  float* __restrict__ out) {
    __shared__ float pmin[4][Sn];
    __shared__ float db[Sn];
    __shared__ float hb[128];
    __shared__ float part[Cn][32];
    const int b = blockIdx.x >> 2, g = blockIdx.x & 3, tid = threadIdx.x;

    {
        const int s = tid & 127, cg = tid >> 7;
        const float* pp = partial + (b * NCH + cg * 4) * Sn + s;
        float m = pp[0];
        #pragma unroll
        for (int c = 1; c < 4; ++c) m = fminf(m, pp[c * Sn]);
        pmin[cg][s] = m;
    }
    __syncthreads();
    if (tid < Sn) {
        const float m = fminf(fminf(pmin[0][tid], pmin[1][tid]),
                              fminf(pmin[2][tid], pmin[3][tid]));
        db[tid] = m;
        if (g == 0) out[b * Sn + tid] = m;     // distance output
    }
    __syncthreads();

    if (tid < 128) {                            // h rows g*128 .. +127
        const int hrow = g * 128 + tid;
        float a = b1[hrow];
        const float4* w1r = (const float4*)(W1 + hrow * Sn);
        const float4* dbv = (const float4*)db;
        #pragma unroll
        for (int i = 0; i < Sn / 4; ++i) {
            const float4 wv = w1r[i];
            const float4 dv = dbv[i];
            a = fmaf(dv.x, wv.x, a); a = fmaf(dv.y, wv.y, a);
            a = fmaf(dv.z, wv.z, a); a = fmaf(dv.w, wv.w, a);
        }
        hb[tid] = fmaxf(a, 0.0f);
    }
    __syncthreads();

    if (tid < Cn * 32) {
        const int c = tid >> 5, p = tid & 31;
        float acc = 0.f;
        #pragma unroll
        for (int k = 0; k < 4; ++k)
            acc = fmaf(hb[p + 32 * k], W2[c * Hn + g * 128 + p + 32 * k], acc);
        part[c][p] = acc;
    }
    __syncthreads();
    if (tid < Cn) {
        float acc = 0.f;
        #pragma unroll
        for (int p = 0; p < 32; ++p) acc += part[tid][p];
        atomicAdd(&out[Bn * Sn + b * Cn + tid], acc);   // b2 pre-added by prep
    }
}

// ----------------------------------------------------------------- launcher
extern "C" void kernel_launch(void* const* d_in, const int* in_sizes, int n_in,
                              void* d_out, int out_size, void* d_ws, size_t ws_size,
                              hipStream_t stream) {
    const float* x  = (const float*)d_in[0];
    const float* sh = (const float*)d_in[1];
    const float* W1 = (const float*)d_in[2];
    const float* b1 = (const float*)d_in[3];
    const float* W2 = (const float*)d_in[4];
    const float* b2 = (const float*)d_in[5];
    float* out = (float*)d_out;

    char* wsb = (char*)d_ws;
    float*        partial = (float*)wsb;                    // 262144 B
    unsigned int* shb     = (unsigned int*)(wsb + 262144);  //  12288 B
    float*        shsq_g  = (float*)(wsb + 274432);         //    512 B
    float*        wsqT    = (float*)(wsb + 278528);         //   2 MiB
    unsigned int* xbf     = (unsigned int*)(wsb + 2375680); //   3.2 MiB

    prep_kernel<<<513, 256, 0, stream>>>(x, sh, b2, shb, shsq_g, wsqT, xbf, out);
    dist_kernel<<<Bn * NCH * 2, 256, 0, stream>>>(shb, shsq_g, wsqT, xbf, partial);
    mlp_kernel<<<Bn * 4, 512, 0, stream>>>(partial, W1, b1, W2, out);
}